// Round 14
// baseline (185.973 us; speedup 1.0000x reference)
//
#include <hip/hip_runtime.h>

#define HH 192
#define WW 256
#define CCH 4             // channels per chunk
#define NCHUNK 16         // 64 / 4
#define THREADS 576       // 9 waves; wave w handles i = w - 4
#define CHSTEP (CCH * HH * WW)
#define ROWF 264          // band row: cols -4..259 (66 x 16B units)
#define CHF  (9 * ROWF)   // 2376 floats per channel (9 band rows)
#define BUFF (CCH * CHF)  // 9504 floats per buffer
#define NUNITS (CCH * 9 * 66)   // 2376 16B units per chunk

typedef float f4 __attribute__((ext_vector_type(4)));

// async global->LDS, 16B per lane, dest = wave-uniform base + lane*16
#define GLL(gp, lp) __builtin_amdgcn_global_load_lds(                        \
    (const __attribute__((address_space(1))) unsigned int*)(gp),            \
    (__attribute__((address_space(3))) unsigned int*)(lp), 16, 0, 0)

// R14: conflict model unified over R6-R13 (all 8 data points):
//   ds_read_b128 is FREE iff the wave's 64 lanes read ONE contiguous 1024B
//   run (any 16B-aligned offset). Any row-split layout pays ~4 cyc/instr
//   (R8/R11/R13 all = 4 x (x2 reads); R6 misaligned = 8; x1 [lane*4] and
//   R12's reads = 0). So: block = 1 output row x 256 px, wave = i-shift,
//   lane*4 px. Wave w reads only band row 8-w -> every xv0/1/2 read is
//   row_base + lane*16 + {0,16,32}B = contiguous -> 0 conflicts.
// x2-only LDS (74.25KB dbuf < 80KB -> 2 blocks/CU). x1 is lane-unique ->
// 4 direct global f4 loads/chunk, broadcast across the 9 waves by L1.
// Grid: b = bid&7 (one batch per XCD -> L2 reuse of h-adjacent bands).
__global__ __launch_bounds__(THREADS) void cost_volume_kernel(
    const float* __restrict__ x1, const float* __restrict__ x2,
    float* __restrict__ out)
{
    __shared__ __align__(16) float smem[2 * BUFF];   // 76032 B

    const int tid  = threadIdx.x;
    const int wave = tid >> 6;      // 0..8 -> i = wave - 4
    const int lane = tid & 63;      // 64 col groups of 4 px

    const int bid = blockIdx.x;
    const int b   = bid & 7;        // batch -> XCD affinity
    const int h   = bid >> 3;       // 0..191 output row

    // ---- x2 staging: 2376 units = 37 full strips + 1 partial ----
    // unit u -> ch=u/594, v=u%594, row=v/66, cu=v%66; col = cu*4-4.
    // LDS float offset = 4u (linear). wave w: strips {w,w+9,w+18,w+27},
    // waves 0,1 also take strips {36,37}.
    auto desc = [&](int s, int& goff) {   // -1 if masked
        const int u = (s << 6) + lane;
        const int ch = u / 594, v = u % 594;
        const int row = v / 66, cu = v % 66;
        const int hg = h + row - 4, wg = (cu << 2) - 4;
        const bool ok = (u < NUNITS) & (cu >= 1) & (cu <= 64) &
                        (hg >= 0) & (hg < HH);
        goff = ok ? (((b * 64 + ch) * HH + hg) * WW + wg) : -1;
    };
    int g0, g1, g2, g3, g4;
    desc(wave,      g0);
    desc(wave + 9,  g1);
    desc(wave + 18, g2);
    desc(wave + 27, g3);
    desc(wave + 36, g4);            // real work only for waves 0,1

    auto issue = [&](int nb, int n) {
        const int cofs = n * CHSTEP;
        float* const base = smem + nb * BUFF;
        if (g0 >= 0) GLL(x2 + g0 + cofs, base + (wave << 8));
        if (g1 >= 0) GLL(x2 + g1 + cofs, base + ((wave + 9) << 8));
        if (g2 >= 0) GLL(x2 + g2 + cofs, base + ((wave + 18) << 8));
        if (g3 >= 0) GLL(x2 + g3 + cofs, base + ((wave + 27) << 8));
        if (g4 >= 0) GLL(x2 + g4 + cofs, base + ((wave + 36) << 8));
    };

    // ---- pre-zero LDS (halo/OOB slots persist as zeros) ----
    const f4 z4 = {0.f, 0.f, 0.f, 0.f};
    for (int z = tid; z < 2 * BUFF / 4; z += THREADS) ((f4*)smem)[z] = z4;
    __syncthreads();

    issue(0, 0);
    __syncthreads();   // drains vmcnt(0) before s_barrier

    f4 acc0 = z4, acc1 = z4, acc2 = z4, acc3 = z4, acc4 = z4,
       acc5 = z4, acc6 = z4, acc7 = z4, acc8 = z4;

    const int row2 = 8 - wave;      // this wave's band row
    // x1 direct-load base: lane-unique f4, channel 0
    const float* x1base = x1 + ((b * 64) * HH + h) * WW + (lane << 2);

    for (int n = 0; n < NCHUNK; ++n) {
        if (n + 1 < NCHUNK) issue((n + 1) & 1, n + 1);
        const float* x1c = x1base + n * CHSTEP;
        const f4 a0 = *(const f4*)(x1c);
        const f4 a1 = *(const f4*)(x1c + HH * WW);
        const f4 a2 = *(const f4*)(x1c + 2 * HH * WW);
        const f4 a3 = *(const f4*)(x1c + 3 * HH * WW);
        const float* sb2 = smem + (n & 1) * BUFF + row2 * ROWF + (lane << 2);

#define CV_CC(CC, AV)                                                        \
        {                                                                    \
            const f4 xv0 = *(const f4*)(sb2 + (CC) * CHF);                   \
            const f4 xv1 = *(const f4*)(sb2 + (CC) * CHF + 4);               \
            const f4 xv2 = *(const f4*)(sb2 + (CC) * CHF + 8);               \
            const f4 w8 = xv0;                                               \
            const f4 w7 = __builtin_shufflevector(xv0, xv1, 1, 2, 3, 4);     \
            const f4 w6 = __builtin_shufflevector(xv0, xv1, 2, 3, 4, 5);     \
            const f4 w5 = __builtin_shufflevector(xv0, xv1, 3, 4, 5, 6);     \
            const f4 w4 = xv1;                                               \
            const f4 w3 = __builtin_shufflevector(xv1, xv2, 1, 2, 3, 4);     \
            const f4 w2 = __builtin_shufflevector(xv1, xv2, 2, 3, 4, 5);     \
            const f4 w1w = __builtin_shufflevector(xv1, xv2, 3, 4, 5, 6);    \
            const f4 w0w = xv2;                                              \
            acc0 = __builtin_elementwise_fma(AV, w0w, acc0);                 \
            acc1 = __builtin_elementwise_fma(AV, w1w, acc1);                 \
            acc2 = __builtin_elementwise_fma(AV, w2, acc2);                  \
            acc3 = __builtin_elementwise_fma(AV, w3, acc3);                  \
            acc4 = __builtin_elementwise_fma(AV, w4, acc4);                  \
            acc5 = __builtin_elementwise_fma(AV, w5, acc5);                  \
            acc6 = __builtin_elementwise_fma(AV, w6, acc6);                  \
            acc7 = __builtin_elementwise_fma(AV, w7, acc7);                  \
            acc8 = __builtin_elementwise_fma(AV, w8, acc8);                  \
        }
        CV_CC(0, a0)
        CV_CC(1, a1)
        CV_CC(2, a2)
        CV_CC(3, a3)
#undef CV_CC
        __syncthreads();
    }

    // ---- epilogue ----
    const float scale = 1.0f / 81.0f;
    const int wout = lane << 2;
    // k = (9*i + j) mod 81 = (9*wave + jj + 41) mod 81
#define CV_OUT(JJ)                                                           \
    {                                                                        \
        const int k = (9 * wave + (JJ) + 41) % 81;                           \
        float* po = out + (((long)b * 81 + k) * HH + h) * WW + wout;         \
        *(f4*)po = acc##JJ * scale;                                          \
    }
    CV_OUT(0) CV_OUT(1) CV_OUT(2) CV_OUT(3) CV_OUT(4)
    CV_OUT(5) CV_OUT(6) CV_OUT(7) CV_OUT(8)
#undef CV_OUT
}

extern "C" void kernel_launch(void* const* d_in, const int* in_sizes, int n_in,
                              void* d_out, int out_size, void* d_ws, size_t ws_size,
                              hipStream_t stream) {
    const float* x1 = (const float*)d_in[0];
    const float* x2 = (const float*)d_in[1];
    float* out = (float*)d_out;
    dim3 grid(8 * 192);   // 1536 blocks: batch (XCD-affine) x 192 rows
    dim3 block(THREADS);
    hipLaunchKernelGGL(cost_volume_kernel, grid, block, 0, stream, x1, x2, out);
}

// Round 15
// 159.260 us; speedup vs baseline: 1.1677x; 1.1677x over previous
//
#include <hip/hip_runtime.h>

#define HH 192
#define WW 256
#define CCH 4             // channels per chunk
#define NCHUNK 16         // 64 / 4
#define THREADS 576       // 9 waves; wave w handles i = w - 4
#define CHSTEP (CCH * HH * WW)
#define ROWF 264          // band row: cols -4..259 (66 x 16B units)
#define CHF  (9 * ROWF)   // 2376 floats per channel (9 band rows)
#define BUFF (CCH * CHF)  // 9504 floats per buffer
#define NUNITS (CCH * 9 * 66)   // 2376 16B units per chunk

typedef float f4 __attribute__((ext_vector_type(4)));

// async global->LDS, 16B per lane, dest = wave-uniform base + lane*16
#define GLL(gp, lp) __builtin_amdgcn_global_load_lds(                        \
    (const __attribute__((address_space(1))) unsigned int*)(gp),            \
    (__attribute__((address_space(3))) unsigned int*)(lp), 16, 0, 0)

// R14 established (conflicts==0): ds_read_b128 is free iff the wave's 64
// lanes read one contiguous 1024B run. Block = 1 row x 256 px, wave = i,
// lane*4 px; wave w reads only band row 8-w -> all LDS reads contiguous.
// R15 fix: R14 consumed x1 global loads at the TOP of each chunk; their
// vmcnt wait (GLL shares vmcnt) drained the whole next-chunk prefetch
// before any FMA -> latency-serialized (VALUBusy 22%). Now x1 is register-
// pipelined one chunk ahead: consume regs loaded last iteration, issue
// x1(n+1) AFTER the FMAs (hides under the barrier's GLL drain). Compute
// phase has zero vmem waits, exactly like R11's overlap, plus 0 conflicts.
__global__ __launch_bounds__(THREADS) void cost_volume_kernel(
    const float* __restrict__ x1, const float* __restrict__ x2,
    float* __restrict__ out)
{
    __shared__ __align__(16) float smem[2 * BUFF];   // 76032 B

    const int tid  = threadIdx.x;
    const int wave = tid >> 6;      // 0..8 -> i = wave - 4
    const int lane = tid & 63;      // 64 col groups of 4 px

    const int bid = blockIdx.x;
    const int b   = bid & 7;        // batch -> XCD affinity
    const int h   = bid >> 3;       // 0..191 output row

    // ---- x2 staging: 2376 units = 37 full strips + 1 partial ----
    // unit u -> ch=u/594, v=u%594, row=v/66, cu=v%66; col = cu*4-4.
    // LDS float offset = 4u (linear). wave w: strips {w,w+9,w+18,w+27},
    // waves 0,1 also take strips {36,37}.
    auto desc = [&](int s, int& goff) {   // -1 if masked
        const int u = (s << 6) + lane;
        const int ch = u / 594, v = u % 594;
        const int row = v / 66, cu = v % 66;
        const int hg = h + row - 4, wg = (cu << 2) - 4;
        const bool ok = (u < NUNITS) & (cu >= 1) & (cu <= 64) &
                        (hg >= 0) & (hg < HH);
        goff = ok ? (((b * 64 + ch) * HH + hg) * WW + wg) : -1;
    };
    int g0, g1, g2, g3, g4;
    desc(wave,      g0);
    desc(wave + 9,  g1);
    desc(wave + 18, g2);
    desc(wave + 27, g3);
    desc(wave + 36, g4);            // real work only for waves 0,1

    auto issue = [&](int nb, int n) {
        const int cofs = n * CHSTEP;
        float* const base = smem + nb * BUFF;
        if (g0 >= 0) GLL(x2 + g0 + cofs, base + (wave << 8));
        if (g1 >= 0) GLL(x2 + g1 + cofs, base + ((wave + 9) << 8));
        if (g2 >= 0) GLL(x2 + g2 + cofs, base + ((wave + 18) << 8));
        if (g3 >= 0) GLL(x2 + g3 + cofs, base + ((wave + 27) << 8));
        if (g4 >= 0) GLL(x2 + g4 + cofs, base + ((wave + 36) << 8));
    };

    // ---- pre-zero LDS (halo/OOB slots persist as zeros) ----
    const f4 z4 = {0.f, 0.f, 0.f, 0.f};
    for (int z = tid; z < 2 * BUFF / 4; z += THREADS) ((f4*)smem)[z] = z4;
    __syncthreads();

    // x1 direct-load base: lane-unique f4, channel 0
    const float* x1base = x1 + ((b * 64) * HH + h) * WW + (lane << 2);

    issue(0, 0);
    // preload x1 chunk 0 (latency covered by the same barrier drain)
    f4 a0 = *(const f4*)(x1base);
    f4 a1 = *(const f4*)(x1base + HH * WW);
    f4 a2 = *(const f4*)(x1base + 2 * HH * WW);
    f4 a3 = *(const f4*)(x1base + 3 * HH * WW);
    __syncthreads();   // drains vmcnt(0) before s_barrier

    f4 acc0 = z4, acc1 = z4, acc2 = z4, acc3 = z4, acc4 = z4,
       acc5 = z4, acc6 = z4, acc7 = z4, acc8 = z4;

    const int row2 = 8 - wave;      // this wave's band row

    for (int n = 0; n < NCHUNK; ++n) {
        if (n + 1 < NCHUNK) issue((n + 1) & 1, n + 1);
        const float* sb2 = smem + (n & 1) * BUFF + row2 * ROWF + (lane << 2);

#define CV_CC(CC, AV)                                                        \
        {                                                                    \
            const f4 xv0 = *(const f4*)(sb2 + (CC) * CHF);                   \
            const f4 xv1 = *(const f4*)(sb2 + (CC) * CHF + 4);               \
            const f4 xv2 = *(const f4*)(sb2 + (CC) * CHF + 8);               \
            const f4 w8 = xv0;                                               \
            const f4 w7 = __builtin_shufflevector(xv0, xv1, 1, 2, 3, 4);     \
            const f4 w6 = __builtin_shufflevector(xv0, xv1, 2, 3, 4, 5);     \
            const f4 w5 = __builtin_shufflevector(xv0, xv1, 3, 4, 5, 6);     \
            const f4 w4 = xv1;                                               \
            const f4 w3 = __builtin_shufflevector(xv1, xv2, 1, 2, 3, 4);     \
            const f4 w2 = __builtin_shufflevector(xv1, xv2, 2, 3, 4, 5);     \
            const f4 w1w = __builtin_shufflevector(xv1, xv2, 3, 4, 5, 6);    \
            const f4 w0w = xv2;                                              \
            acc0 = __builtin_elementwise_fma(AV, w0w, acc0);                 \
            acc1 = __builtin_elementwise_fma(AV, w1w, acc1);                 \
            acc2 = __builtin_elementwise_fma(AV, w2, acc2);                  \
            acc3 = __builtin_elementwise_fma(AV, w3, acc3);                  \
            acc4 = __builtin_elementwise_fma(AV, w4, acc4);                  \
            acc5 = __builtin_elementwise_fma(AV, w5, acc5);                  \
            acc6 = __builtin_elementwise_fma(AV, w6, acc6);                  \
            acc7 = __builtin_elementwise_fma(AV, w7, acc7);                  \
            acc8 = __builtin_elementwise_fma(AV, w8, acc8);                  \
        }
        CV_CC(0, a0)
        CV_CC(1, a1)
        CV_CC(2, a2)
        CV_CC(3, a3)
#undef CV_CC

        // x1 register-prefetch for chunk n+1 (issued after last use of
        // a0..a3; waited on implicitly by the barrier's vmcnt(0) drain)
        if (n + 1 < NCHUNK) {
            const float* x1c = x1base + (n + 1) * CHSTEP;
            a0 = *(const f4*)(x1c);
            a1 = *(const f4*)(x1c + HH * WW);
            a2 = *(const f4*)(x1c + 2 * HH * WW);
            a3 = *(const f4*)(x1c + 3 * HH * WW);
        }
        __syncthreads();
    }

    // ---- epilogue ----
    const float scale = 1.0f / 81.0f;
    const int wout = lane << 2;
    // k = (9*i + j) mod 81 = (9*wave + jj + 41) mod 81
#define CV_OUT(JJ)                                                           \
    {                                                                        \
        const int k = (9 * wave + (JJ) + 41) % 81;                           \
        float* po = out + (((long)b * 81 + k) * HH + h) * WW + wout;         \
        *(f4*)po = acc##JJ * scale;                                          \
    }
    CV_OUT(0) CV_OUT(1) CV_OUT(2) CV_OUT(3) CV_OUT(4)
    CV_OUT(5) CV_OUT(6) CV_OUT(7) CV_OUT(8)
#undef CV_OUT
}

extern "C" void kernel_launch(void* const* d_in, const int* in_sizes, int n_in,
                              void* d_out, int out_size, void* d_ws, size_t ws_size,
                              hipStream_t stream) {
    const float* x1 = (const float*)d_in[0];
    const float* x2 = (const float*)d_in[1];
    float* out = (float*)d_out;
    dim3 grid(8 * 192);   // 1536 blocks: batch (XCD-affine) x 192 rows
    dim3 block(THREADS);
    hipLaunchKernelGGL(cost_volume_kernel, grid, block, 0, stream, x1, x2, out);
}